// Round 1
// baseline (1903.219 us; speedup 1.0000x reference)
//
#include <hip/hip_runtime.h>
#include <cstdint>
#include <cstddef>

#define N_NODES 100000
#define N_EDGES 1600000
// D_NODE=256, D_MSG=128, D_RBF=32, H=8, D_HEAD=16

// ---- workspace layout (float offsets) ----
#define OFF_XLR    ((size_t)0)                            // N*256 : [xl | xr] per node
#define OFF_LOGIT  (OFF_XLR    + (size_t)N_NODES*256)     // E*8
#define OFF_DENOM  (OFF_LOGIT  + (size_t)N_EDGES*8)       // N*8
#define OFF_RBFSUM (OFF_DENOM  + (size_t)N_NODES*8)       // N*32
#define OFF_DEG    (OFF_RBFSUM + (size_t)N_NODES*32)      // N
#define OFF_PLOOP  (OFF_DEG    + (size_t)N_NODES)         // N*8
#define OFF_ACC    (OFF_PLOOP  + (size_t)N_NODES*8)       // N*128
#define OFF_WCAT   (OFF_ACC    + (size_t)N_NODES*128)     // 256*256  (Wl@W_n2m ; Wr@W_n2m)
#define OFF_BCAT   (OFF_WCAT   + 65536)                   // 256
#define OFF_WCOMBT (OFF_BCAT   + 256)                     // 32*128   (We@W_r2m, stored [j][o])
// total ~56.17M floats ~225 MB

#define EPB 32  // edges per block (E % EPB == 0)

// ---------------- zero-init ----------------
__global__ void k_zero(float* __restrict__ p, size_t n4) {
  size_t i = (size_t)blockIdx.x * blockDim.x + threadIdx.x;
  size_t stride = (size_t)gridDim.x * blockDim.x;
  float4 z = make_float4(0.f, 0.f, 0.f, 0.f);
  for (; i < n4; i += stride) ((float4*)p)[i] = z;
}

// ---------------- fold weights ----------------
// Wcat[o][i] (256x256): rows 0..127 = Wl@W_n2m, rows 128..255 = Wr@W_n2m
// bcat[256] = [bl | br]
// WcombT[j][o] (32x128): (We@W_r2m) transposed
__global__ void k_weights(const float* __restrict__ Wl, const float* __restrict__ Wr,
                          const float* __restrict__ We, const float* __restrict__ W_n2m,
                          const float* __restrict__ W_r2m, const float* __restrict__ bl,
                          const float* __restrict__ br,
                          float* __restrict__ Wcat, float* __restrict__ bcat,
                          float* __restrict__ WcombT) {
  int idx = blockIdx.x * blockDim.x + threadIdx.x;
  if (idx < 65536) {
    int o = idx >> 8, i = idx & 255;
    const float* wrow = (o < 128) ? (Wl + o * 128) : (Wr + (o - 128) * 128);
    float s = 0.f;
    for (int k = 0; k < 128; ++k) s += wrow[k] * W_n2m[k * 256 + i];
    Wcat[idx] = s;
  } else if (idx < 65536 + 256) {
    int o = idx - 65536;
    bcat[o] = (o < 128) ? bl[o] : br[o - 128];
  } else if (idx < 65536 + 256 + 4096) {
    int q = idx - (65536 + 256);
    int j = q >> 7, o = q & 127;
    float s = 0.f;
    for (int k = 0; k < 128; ++k) s += We[o * 128 + k] * W_r2m[k * 32 + j];
    WcombT[q] = s;
  }
}

// ---------------- generic f32 GEMM: C[M][NC] = A[M][K] @ B[NC][K]^T (+bias) ----------------
// BM=BN=64, BK=16, 256 threads, 4x4 per thread. NC, K multiples of 16; NC multiple of 64.
template <bool HAS_BIAS>
__global__ __launch_bounds__(256) void gemm_tn(const float* __restrict__ A,
                                               const float* __restrict__ B,
                                               const float* __restrict__ bias,
                                               float* __restrict__ C, int M, int NC, int K) {
  __shared__ __align__(16) float As[16][68];
  __shared__ __align__(16) float Bs[16][68];
  const int tid = threadIdx.x;
  const int tx = tid & 15, ty = tid >> 4;
  const int rowBase = blockIdx.x * 64;
  const int colBase = blockIdx.y * 64;
  const int lr = tid >> 2;          // 0..63
  const int lk = (tid & 3) << 2;    // 0,4,8,12
  float c[4][4];
#pragma unroll
  for (int i = 0; i < 4; ++i)
#pragma unroll
    for (int j = 0; j < 4; ++j) c[i][j] = 0.f;

  for (int k0 = 0; k0 < K; k0 += 16) {
    const int ar = rowBase + lr;
    float4 av = make_float4(0.f, 0.f, 0.f, 0.f);
    if (ar < M) av = *(const float4*)(A + (size_t)ar * K + k0 + lk);
    const int bc = colBase + lr;
    float4 bv = *(const float4*)(B + (size_t)bc * K + k0 + lk);
    __syncthreads();
    As[lk + 0][lr] = av.x; As[lk + 1][lr] = av.y; As[lk + 2][lr] = av.z; As[lk + 3][lr] = av.w;
    Bs[lk + 0][lr] = bv.x; Bs[lk + 1][lr] = bv.y; Bs[lk + 2][lr] = bv.z; Bs[lk + 3][lr] = bv.w;
    __syncthreads();
#pragma unroll
    for (int k = 0; k < 16; ++k) {
      float4 a = *(const float4*)&As[k][ty << 2];
      float4 b = *(const float4*)&Bs[k][tx << 2];
      c[0][0] += a.x * b.x; c[0][1] += a.x * b.y; c[0][2] += a.x * b.z; c[0][3] += a.x * b.w;
      c[1][0] += a.y * b.x; c[1][1] += a.y * b.y; c[1][2] += a.y * b.z; c[1][3] += a.y * b.w;
      c[2][0] += a.z * b.x; c[2][1] += a.z * b.y; c[2][2] += a.z * b.z; c[2][3] += a.z * b.w;
      c[3][0] += a.w * b.x; c[3][1] += a.w * b.y; c[3][2] += a.w * b.z; c[3][3] += a.w * b.w;
    }
  }
#pragma unroll
  for (int i = 0; i < 4; ++i) {
    const int r = rowBase + (ty << 2) + i;
    if (r < M) {
      const int col = colBase + (tx << 2);
      float4 v;
      v.x = c[i][0]; v.y = c[i][1]; v.z = c[i][2]; v.w = c[i][3];
      if (HAS_BIAS) {
        v.x += bias[col + 0]; v.y += bias[col + 1]; v.z += bias[col + 2]; v.w += bias[col + 3];
      }
      *(float4*)(C + (size_t)r * NC + col) = v;
    }
  }
}

// ---------------- edge pass 1: et, logits, denom, rbf_sum, deg ----------------
__global__ __launch_bounds__(128) void k_edge1(
    const float* __restrict__ XLR, const float* __restrict__ rbf,
    const int* __restrict__ src, const int* __restrict__ dst,
    const float* __restrict__ WcombT, const float* __restrict__ att,
    float* __restrict__ logit, float* __restrict__ denom,
    float* __restrict__ rbf_sum, float* __restrict__ deg) {
  __shared__ __align__(16) float rbf_s[EPB][32];
  __shared__ int src_s[EPB], dst_s[EPB];
  const int tid = threadIdx.x;
  const size_t e0 = (size_t)blockIdx.x * EPB;

  float wreg[32];
#pragma unroll
  for (int j = 0; j < 32; ++j) wreg[j] = WcombT[j * 128 + tid];
  const float att_r = att[tid];

#pragma unroll
  for (int t = 0; t < (EPB * 32) / 128; ++t) {
    int idx = t * 128 + tid;
    rbf_s[idx >> 5][idx & 31] = rbf[e0 * 32 + idx];
  }
  if (tid < EPB) src_s[tid] = src[e0 + tid];
  else if (tid < 2 * EPB) dst_s[tid - EPB] = dst[e0 + tid - EPB];
  __syncthreads();

  const int h = tid >> 4;
  for (int i = 0; i < EPB; ++i) {
    const int s = src_s[i], d = dst_s[i];
    float et = 0.f;
    const float4* r4 = (const float4*)rbf_s[i];
#pragma unroll
    for (int j4 = 0; j4 < 8; ++j4) {
      float4 rv = r4[j4];
      et += rv.x * wreg[j4 * 4 + 0] + rv.y * wreg[j4 * 4 + 1] +
            rv.z * wreg[j4 * 4 + 2] + rv.w * wreg[j4 * 4 + 3];
    }
    float u = XLR[(size_t)s * 256 + tid] + XLR[(size_t)d * 256 + 128 + tid] + et;
    u = (u > 0.f) ? u : 0.2f * u;
    float r = u * att_r;
    r += __shfl_xor(r, 1);
    r += __shfl_xor(r, 2);
    r += __shfl_xor(r, 4);
    r += __shfl_xor(r, 8);
    if ((tid & 15) == 0) {
      logit[(e0 + i) * 8 + h] = r;
      atomicAdd(&denom[(size_t)d * 8 + h], __expf(r));
    }
    if (tid < 32) atomicAdd(&rbf_sum[(size_t)d * 32 + tid], rbf_s[i][tid]);
    if (tid == 0) atomicAdd(&deg[d], 1.f);
  }
}

// ---------------- self-loop pass (per node) ----------------
__global__ __launch_bounds__(128) void k_selfloop(
    const float* __restrict__ XLR, const float* __restrict__ rbf_sum,
    const float* __restrict__ deg, const float* __restrict__ WcombT,
    const float* __restrict__ att, float* __restrict__ denom,
    float* __restrict__ p_loop) {
  const int tid = threadIdx.x;
  const int n = blockIdx.x;
  float wreg[32];
#pragma unroll
  for (int j = 0; j < 32; ++j) wreg[j] = WcombT[j * 128 + tid];
  const float att_r = att[tid];
  const float inv = 1.f / fmaxf(deg[n], 1.f);
  float et = 0.f;
  const float4* r4 = (const float4*)(rbf_sum + (size_t)n * 32);
#pragma unroll
  for (int j4 = 0; j4 < 8; ++j4) {
    float4 rv = r4[j4];
    et += rv.x * wreg[j4 * 4 + 0] + rv.y * wreg[j4 * 4 + 1] +
          rv.z * wreg[j4 * 4 + 2] + rv.w * wreg[j4 * 4 + 3];
  }
  et *= inv;
  float u = XLR[(size_t)n * 256 + tid] + XLR[(size_t)n * 256 + 128 + tid] + et;
  u = (u > 0.f) ? u : 0.2f * u;
  float r = u * att_r;
  r += __shfl_xor(r, 1);
  r += __shfl_xor(r, 2);
  r += __shfl_xor(r, 4);
  r += __shfl_xor(r, 8);
  if ((tid & 15) == 0) {
    const int h = tid >> 4;
    const float p = __expf(r);
    p_loop[(size_t)n * 8 + h] = p;
    denom[(size_t)n * 8 + h] += p;  // exclusive per node, after k_edge1
  }
}

// ---------------- edge pass 2: alpha * xl[src] scatter ----------------
__global__ __launch_bounds__(128) void k_edge2(
    const float* __restrict__ XLR, const int* __restrict__ src,
    const int* __restrict__ dst, const float* __restrict__ logit,
    const float* __restrict__ denom, float* __restrict__ acc) {
  __shared__ float lg_s[EPB][8];
  __shared__ int src_s[EPB], dst_s[EPB];
  const int tid = threadIdx.x;
  const size_t e0 = (size_t)blockIdx.x * EPB;
  {
    int idx = tid;
    lg_s[idx >> 3][idx & 7] = logit[e0 * 8 + idx];
    idx += 128;
    lg_s[idx >> 3][idx & 7] = logit[e0 * 8 + idx];
  }
  if (tid < EPB) src_s[tid] = src[e0 + tid];
  else if (tid < 2 * EPB) dst_s[tid - EPB] = dst[e0 + tid - EPB];
  __syncthreads();
  const int h = tid >> 4;
  for (int i = 0; i < EPB; ++i) {
    const int s = src_s[i], d = dst_s[i];
    const float alpha = __expf(lg_s[i][h]) / denom[(size_t)d * 8 + h];
    const float v = alpha * XLR[(size_t)s * 256 + tid];
    atomicAdd(&acc[(size_t)d * 128 + tid], v);
  }
}

// ---------------- self message + bias ----------------
__global__ void k_final_node(const float* __restrict__ XLR, const float* __restrict__ p_loop,
                             const float* __restrict__ denom, const float* __restrict__ bias,
                             float* __restrict__ acc) {
  size_t idx = (size_t)blockIdx.x * blockDim.x + threadIdx.x;
  if (idx >= (size_t)N_NODES * 128) return;
  const int n = (int)(idx >> 7);
  const int o = (int)(idx & 127);
  const int h = o >> 4;
  const float alpha = p_loop[(size_t)n * 8 + h] / denom[(size_t)n * 8 + h];
  acc[idx] += alpha * XLR[(size_t)n * 256 + o] + bias[o];
}

extern "C" void kernel_launch(void* const* d_in, const int* in_sizes, int n_in,
                              void* d_out, int out_size, void* d_ws, size_t ws_size,
                              hipStream_t stream) {
  const float* x     = (const float*)d_in[0];
  const float* rbf   = (const float*)d_in[1];
  const int*   ei    = (const int*)d_in[2];
  const float* W_n2m = (const float*)d_in[4];
  const float* W_r2m = (const float*)d_in[5];
  const float* Wl    = (const float*)d_in[6];
  const float* bl    = (const float*)d_in[7];
  const float* Wr    = (const float*)d_in[8];
  const float* br    = (const float*)d_in[9];
  const float* We    = (const float*)d_in[10];
  const float* att   = (const float*)d_in[11];
  const float* bias  = (const float*)d_in[12];
  const float* W_m2n = (const float*)d_in[13];
  float* out = (float*)d_out;
  float* ws  = (float*)d_ws;

  const int* src = ei;
  const int* dst = ei + N_EDGES;

  float* XLR    = ws + OFF_XLR;
  float* logit  = ws + OFF_LOGIT;
  float* denom  = ws + OFF_DENOM;
  float* rbfsum = ws + OFF_RBFSUM;
  float* deg    = ws + OFF_DEG;
  float* ploop  = ws + OFF_PLOOP;
  float* acc    = ws + OFF_ACC;
  float* Wcat   = ws + OFF_WCAT;
  float* bcat   = ws + OFF_BCAT;
  float* WcombT = ws + OFF_WCOMBT;

  // zero denom..acc contiguous region: N*(8+32+1+8+128) = N*177 floats
  k_zero<<<4096, 256, 0, stream>>>(denom, (size_t)N_NODES * 177 / 4);
  k_weights<<<(65536 + 256 + 4096 + 255) / 256, 256, 0, stream>>>(
      Wl, Wr, We, W_n2m, W_r2m, bl, br, Wcat, bcat, WcombT);
  gemm_tn<true><<<dim3((N_NODES + 63) / 64, 4), 256, 0, stream>>>(
      x, Wcat, bcat, XLR, N_NODES, 256, 256);
  k_edge1<<<N_EDGES / EPB, 128, 0, stream>>>(
      XLR, rbf, src, dst, WcombT, att, logit, denom, rbfsum, deg);
  k_selfloop<<<N_NODES, 128, 0, stream>>>(XLR, rbfsum, deg, WcombT, att, denom, ploop);
  k_edge2<<<N_EDGES / EPB, 128, 0, stream>>>(XLR, src, dst, logit, denom, acc);
  k_final_node<<<((size_t)N_NODES * 128 + 255) / 256, 256, 0, stream>>>(
      XLR, ploop, denom, bias, acc);
  gemm_tn<false><<<dim3((N_NODES + 63) / 64, 4), 256, 0, stream>>>(
      acc, W_m2n, nullptr, out, N_NODES, 256, 128);
}

// Round 2
// 1709.486 us; speedup vs baseline: 1.1133x; 1.1133x over previous
//
#include <hip/hip_runtime.h>
#include <cstdint>
#include <cstddef>

#define N_NODES 100000
#define N_EDGES 1600000
// D_NODE=256, D_MSG=128, D_RBF=32, H=8, D_HEAD=16

// ---- workspace layout (float offsets) ----
// XLR:    N*256                      [xl | xr] f32
// P:      E*8   (exp(logit))         -- accb (bf16) aliases here after edge2
// DENOM:  N*8
// RBFSUM: N*32
// DEG:    N
// PLOOP:  N*8
// ACC:    100096*128 f32 region (12,812,288 floats) -- xb (bf16, 100096x256) aliases here before zero
// BCAT:   256
// WCOMBT: 32*128
// WCATB:  256*256 bf16  (32768 floats)
// WM2NB:  256*128 bf16  (16384 floats)
#define OFF_XLR    ((size_t)0)
#define OFF_P      (OFF_XLR    + (size_t)N_NODES*256)   // 25,600,000
#define OFF_DENOM  (OFF_P      + (size_t)N_EDGES*8)     // 38,400,000
#define OFF_RBFSUM (OFF_DENOM  + (size_t)N_NODES*8)
#define OFF_DEG    (OFF_RBFSUM + (size_t)N_NODES*32)
#define OFF_PLOOP  (OFF_DEG    + (size_t)N_NODES)
#define OFF_ACC    (OFF_PLOOP  + (size_t)N_NODES*8)     // 43,300,000
#define OFF_BCAT   (OFF_ACC    + (size_t)12812288)      // 56,112,288
#define OFF_WCOMBT (OFF_BCAT   + 256)
#define OFF_WCATB  (OFF_WCOMBT + 4096)
#define OFF_WM2NB  (OFF_WCATB  + 32768)
// total = 56,165,792 floats = 224.7 MB (same budget as round 1)

#define M_PAD 100096  // 782*128

#define EPB 32  // edges per block

typedef __attribute__((ext_vector_type(8))) short short8;
typedef __attribute__((ext_vector_type(4))) float float4v;

__device__ __forceinline__ unsigned short f2bf(float f) {
  unsigned u = __float_as_uint(f);
  unsigned r = (u + 0x7fff + ((u >> 16) & 1)) >> 16;
  return (unsigned short)r;
}

// ---------------- zero-init ----------------
__global__ void k_zero(float* __restrict__ p, size_t n4) {
  size_t i = (size_t)blockIdx.x * blockDim.x + threadIdx.x;
  size_t stride = (size_t)gridDim.x * blockDim.x;
  float4 z = make_float4(0.f, 0.f, 0.f, 0.f);
  for (; i < n4; i += stride) ((float4*)p)[i] = z;
}

// ---------------- f32 -> bf16 convert ----------------
__global__ void k_convx(const float* __restrict__ x, unsigned short* __restrict__ xb, unsigned n4) {
  unsigned i = blockIdx.x * blockDim.x + threadIdx.x;
  unsigned stride = gridDim.x * blockDim.x;
  for (; i < n4; i += stride) {
    float4 v = ((const float4*)x)[i];
    ushort4 o;
    o.x = f2bf(v.x); o.y = f2bf(v.y); o.z = f2bf(v.z); o.w = f2bf(v.w);
    ((ushort4*)xb)[i] = o;
  }
}

// ---------------- fold weights ----------------
__global__ void k_weights(const float* __restrict__ Wl, const float* __restrict__ Wr,
                          const float* __restrict__ We, const float* __restrict__ W_n2m,
                          const float* __restrict__ W_r2m, const float* __restrict__ bl,
                          const float* __restrict__ br, const float* __restrict__ W_m2n,
                          unsigned short* __restrict__ WcatB, float* __restrict__ bcat,
                          float* __restrict__ WcombT, unsigned short* __restrict__ Wm2nB) {
  int idx = blockIdx.x * blockDim.x + threadIdx.x;
  if (idx < 65536) {
    int o = idx >> 8, i = idx & 255;
    const float* wrow = (o < 128) ? (Wl + o * 128) : (Wr + (o - 128) * 128);
    float s = 0.f;
    for (int k = 0; k < 128; ++k) s += wrow[k] * W_n2m[k * 256 + i];
    WcatB[idx] = f2bf(s);
  } else if (idx < 65536 + 256) {
    int o = idx - 65536;
    bcat[o] = (o < 128) ? bl[o] : br[o - 128];
  } else if (idx < 65536 + 256 + 4096) {
    int q = idx - (65536 + 256);
    int j = q >> 7, o = q & 127;
    float s = 0.f;
    for (int k = 0; k < 128; ++k) s += We[o * 128 + k] * W_r2m[k * 32 + j];
    WcombT[q] = s;
  } else if (idx < 65536 + 256 + 4096 + 32768) {
    int q = idx - (65536 + 256 + 4096);
    Wm2nB[q] = f2bf(W_m2n[q]);
  }
}

// ---------------- bf16 MFMA GEMM: C[M][NC] = A[M][K] @ B[NC][K]^T (+bias) ----------------
// A, B bf16 row-major; C f32. 128x128 tile, BK=32, 256 thr = 4 waves, each 64x64 (4x4 frags).
// M padded to M_PAD for A reads; NC multiple of 128; K multiple of 32.
template <bool HAS_BIAS>
__global__ __launch_bounds__(256) void gemm_mfma(const unsigned short* __restrict__ A,
                                                 const unsigned short* __restrict__ B,
                                                 const float* __restrict__ bias,
                                                 float* __restrict__ C,
                                                 int M, int NC, int K) {
  __shared__ short As[128 * 32];
  __shared__ short Bs[128 * 32];
  const int tid = threadIdx.x;
  const int lane = tid & 63;
  const int wv = tid >> 6;
  const int rowBase = blockIdx.x << 7;
  const int colBase = blockIdx.y << 7;
  const int wrow = (wv & 1) << 6;
  const int wcol = (wv >> 1) << 6;

  const int srow = tid >> 2;        // 0..63
  const int skc = (tid & 3) << 3;   // 0,8,16,24 (bf16 elems)

  const int n0 = lane & 15;
  const int q = lane >> 4;

  float4v acc[4][4];
#pragma unroll
  for (int i = 0; i < 4; ++i)
#pragma unroll
    for (int j = 0; j < 4; ++j) acc[i][j] = (float4v)(0.f);

  for (int k0 = 0; k0 < K; k0 += 32) {
    const unsigned aoff0 = (unsigned)(rowBase + srow) * K + k0 + skc;
    const unsigned aoff1 = (unsigned)(rowBase + 64 + srow) * K + k0 + skc;
    const unsigned boff0 = (unsigned)(colBase + srow) * K + k0 + skc;
    const unsigned boff1 = (unsigned)(colBase + 64 + srow) * K + k0 + skc;
    uint4 a0 = *(const uint4*)(A + aoff0);
    uint4 a1 = *(const uint4*)(A + aoff1);
    uint4 b0 = *(const uint4*)(B + boff0);
    uint4 b1 = *(const uint4*)(B + boff1);
    __syncthreads();
    ((uint4*)As)[tid] = a0;
    ((uint4*)As)[256 + tid] = a1;
    ((uint4*)Bs)[tid] = b0;
    ((uint4*)Bs)[256 + tid] = b1;
    __syncthreads();

    short8 af[4], bf[4];
    const short8* Ap = (const short8*)As;
    const short8* Bp = (const short8*)Bs;
#pragma unroll
    for (int i = 0; i < 4; ++i) af[i] = Ap[(wrow + i * 16 + n0) * 4 + q];
#pragma unroll
    for (int j = 0; j < 4; ++j) bf[j] = Bp[(wcol + j * 16 + n0) * 4 + q];
#pragma unroll
    for (int i = 0; i < 4; ++i)
#pragma unroll
      for (int j = 0; j < 4; ++j)
        acc[i][j] = __builtin_amdgcn_mfma_f32_16x16x32_bf16(af[i], bf[j], acc[i][j], 0, 0, 0);
  }

#pragma unroll
  for (int j = 0; j < 4; ++j) {
    const int col = colBase + wcol + j * 16 + n0;
    const float bv = HAS_BIAS ? bias[col] : 0.f;
#pragma unroll
    for (int i = 0; i < 4; ++i) {
      const int row0 = rowBase + wrow + i * 16 + (q << 2);
#pragma unroll
      for (int r = 0; r < 4; ++r) {
        const int row = row0 + r;
        if (row < M) C[(unsigned)row * NC + col] = acc[i][j][r] + bv;
      }
    }
  }
}

// ---------------- edge pass 1: et, p=exp(logit), denom, rbf_sum, deg ----------------
__global__ __launch_bounds__(128) void k_edge1(
    const float* __restrict__ XLR, const float* __restrict__ rbf,
    const int* __restrict__ src, const int* __restrict__ dst,
    const float* __restrict__ WcombT, const float* __restrict__ att,
    float* __restrict__ pbuf, float* __restrict__ denom,
    float* __restrict__ rbf_sum, float* __restrict__ deg) {
  __shared__ __align__(16) float rbf_s[EPB][32];
  __shared__ int src_s[EPB], dst_s[EPB];
  const int tid = threadIdx.x;
  const unsigned e0 = blockIdx.x * EPB;

  float wreg[32];
#pragma unroll
  for (int j = 0; j < 32; ++j) wreg[j] = WcombT[j * 128 + tid];
  const float att_r = att[tid];

#pragma unroll
  for (int t = 0; t < (EPB * 32) / 128; ++t) {
    int idx = t * 128 + tid;
    rbf_s[idx >> 5][idx & 31] = rbf[(size_t)e0 * 32 + idx];
  }
  if (tid < EPB) src_s[tid] = src[e0 + tid];
  else if (tid < 2 * EPB) dst_s[tid - EPB] = dst[e0 + tid - EPB];
  __syncthreads();

  const int h = tid >> 4;
  for (int i = 0; i < EPB; ++i) {
    const unsigned s = (unsigned)src_s[i], d = (unsigned)dst_s[i];
    float et = 0.f;
    const float4* r4 = (const float4*)rbf_s[i];
#pragma unroll
    for (int j4 = 0; j4 < 8; ++j4) {
      float4 rv = r4[j4];
      et += rv.x * wreg[j4 * 4 + 0] + rv.y * wreg[j4 * 4 + 1] +
            rv.z * wreg[j4 * 4 + 2] + rv.w * wreg[j4 * 4 + 3];
    }
    float u = XLR[(s << 8) + tid] + XLR[(d << 8) + 128 + tid] + et;
    u = (u > 0.f) ? u : 0.2f * u;
    float r = u * att_r;
    r += __shfl_xor(r, 1);
    r += __shfl_xor(r, 2);
    r += __shfl_xor(r, 4);
    r += __shfl_xor(r, 8);
    if ((tid & 15) == 0) {
      const float p = __expf(r);
      pbuf[((e0 + i) << 3) + h] = p;
      atomicAdd(&denom[(d << 3) + h], p);
    }
    if (tid < 32) atomicAdd(&rbf_sum[(d << 5) + tid], rbf_s[i][tid]);
    if (tid == 0) atomicAdd(&deg[d], 1.f);
  }
}

// ---------------- self-loop pass (per node) ----------------
__global__ __launch_bounds__(128) void k_selfloop(
    const float* __restrict__ XLR, const float* __restrict__ rbf_sum,
    const float* __restrict__ deg, const float* __restrict__ WcombT,
    const float* __restrict__ att, float* __restrict__ denom,
    float* __restrict__ p_loop) {
  const int tid = threadIdx.x;
  const unsigned n = blockIdx.x;
  float wreg[32];
#pragma unroll
  for (int j = 0; j < 32; ++j) wreg[j] = WcombT[j * 128 + tid];
  const float att_r = att[tid];
  const float inv = 1.f / fmaxf(deg[n], 1.f);
  float et = 0.f;
  const float4* r4 = (const float4*)(rbf_sum + ((size_t)n << 5));
#pragma unroll
  for (int j4 = 0; j4 < 8; ++j4) {
    float4 rv = r4[j4];
    et += rv.x * wreg[j4 * 4 + 0] + rv.y * wreg[j4 * 4 + 1] +
          rv.z * wreg[j4 * 4 + 2] + rv.w * wreg[j4 * 4 + 3];
  }
  et *= inv;
  float u = XLR[(n << 8) + tid] + XLR[(n << 8) + 128 + tid] + et;
  u = (u > 0.f) ? u : 0.2f * u;
  float r = u * att_r;
  r += __shfl_xor(r, 1);
  r += __shfl_xor(r, 2);
  r += __shfl_xor(r, 4);
  r += __shfl_xor(r, 8);
  if ((tid & 15) == 0) {
    const int h = tid >> 4;
    const float p = __expf(r);
    p_loop[(n << 3) + h] = p;
    denom[(n << 3) + h] += p;  // exclusive per node, after k_edge1
  }
}

// ---------------- edge pass 2: alpha * xl[src] scatter ----------------
__global__ __launch_bounds__(128) void k_edge2(
    const float* __restrict__ XLR, const int* __restrict__ src,
    const int* __restrict__ dst, const float* __restrict__ pbuf,
    const float* __restrict__ denom, float* __restrict__ acc) {
  __shared__ float p_s[EPB][8];
  __shared__ int src_s[EPB], dst_s[EPB];
  const int tid = threadIdx.x;
  const unsigned e0 = blockIdx.x * EPB;
  {
    int idx = tid;
    p_s[idx >> 3][idx & 7] = pbuf[((size_t)e0 << 3) + idx];
    idx += 128;
    p_s[idx >> 3][idx & 7] = pbuf[((size_t)e0 << 3) + idx];
  }
  if (tid < EPB) src_s[tid] = src[e0 + tid];
  else if (tid < 2 * EPB) dst_s[tid - EPB] = dst[e0 + tid - EPB];
  __syncthreads();
  const int h = tid >> 4;
  for (int i = 0; i < EPB; ++i) {
    const unsigned s = (unsigned)src_s[i], d = (unsigned)dst_s[i];
    const float alpha = p_s[i][h] / denom[(d << 3) + h];
    const float v = alpha * XLR[(s << 8) + tid];
    atomicAdd(&acc[(d << 7) + tid], v);
  }
}

// ---------------- self message + bias -> bf16 acc ----------------
__global__ void k_final_node(const float* __restrict__ XLR, const float* __restrict__ p_loop,
                             const float* __restrict__ denom, const float* __restrict__ bias,
                             const float* __restrict__ acc, unsigned short* __restrict__ accb) {
  unsigned idx = blockIdx.x * blockDim.x + threadIdx.x;
  if (idx >= (unsigned)N_NODES * 128u) return;
  const unsigned n = idx >> 7;
  const unsigned o = idx & 127;
  const unsigned h = o >> 4;
  const float alpha = p_loop[(n << 3) + h] / denom[(n << 3) + h];
  const float v = acc[idx] + alpha * XLR[(n << 8) + o] + bias[o];
  accb[idx] = f2bf(v);
}

extern "C" void kernel_launch(void* const* d_in, const int* in_sizes, int n_in,
                              void* d_out, int out_size, void* d_ws, size_t ws_size,
                              hipStream_t stream) {
  const float* x     = (const float*)d_in[0];
  const float* rbf   = (const float*)d_in[1];
  const int*   ei    = (const int*)d_in[2];
  const float* W_n2m = (const float*)d_in[4];
  const float* W_r2m = (const float*)d_in[5];
  const float* Wl    = (const float*)d_in[6];
  const float* bl    = (const float*)d_in[7];
  const float* Wr    = (const float*)d_in[8];
  const float* br    = (const float*)d_in[9];
  const float* We    = (const float*)d_in[10];
  const float* att   = (const float*)d_in[11];
  const float* bias  = (const float*)d_in[12];
  const float* W_m2n = (const float*)d_in[13];
  float* out = (float*)d_out;
  float* ws  = (float*)d_ws;

  const int* src = ei;
  const int* dst = ei + N_EDGES;

  float* XLR    = ws + OFF_XLR;
  float* P      = ws + OFF_P;
  float* denom  = ws + OFF_DENOM;
  float* rbfsum = ws + OFF_RBFSUM;
  float* deg    = ws + OFF_DEG;
  float* ploop  = ws + OFF_PLOOP;
  float* acc    = ws + OFF_ACC;
  float* bcat   = ws + OFF_BCAT;
  float* WcombT = ws + OFF_WCOMBT;
  unsigned short* WcatB = (unsigned short*)(ws + OFF_WCATB);
  unsigned short* Wm2nB = (unsigned short*)(ws + OFF_WM2NB);
  unsigned short* xb    = (unsigned short*)(ws + OFF_ACC);  // alias: dead before k_zero
  unsigned short* accb  = (unsigned short*)(ws + OFF_P);    // alias: P dead after k_edge2

  // 1. fold weights (+ bf16 conversions)
  k_weights<<<401, 256, 0, stream>>>(Wl, Wr, We, W_n2m, W_r2m, bl, br, W_m2n,
                                     WcatB, bcat, WcombT, Wm2nB);
  // 2. x -> bf16
  k_convx<<<2048, 256, 0, stream>>>(x, xb, (unsigned)(N_NODES * 256 / 4));
  // 3. XLR = x @ [Wl@W_n2m ; Wr@W_n2m]^T + [bl|br]   (bf16 MFMA)
  gemm_mfma<true><<<dim3(M_PAD / 128, 2), 256, 0, stream>>>(
      xb, WcatB, bcat, XLR, N_NODES, 256, 256);
  // 4. zero denom..acc (N*177 floats contiguous)  -- xb dead now
  k_zero<<<4096, 256, 0, stream>>>(denom, (size_t)N_NODES * 177 / 4);
  // 5-7. edge phase
  k_edge1<<<N_EDGES / EPB, 128, 0, stream>>>(
      XLR, rbf, src, dst, WcombT, att, P, denom, rbfsum, deg);
  k_selfloop<<<N_NODES, 128, 0, stream>>>(XLR, rbfsum, deg, WcombT, att, denom, ploop);
  k_edge2<<<N_EDGES / EPB, 128, 0, stream>>>(XLR, src, dst, P, denom, acc);
  // 8. self message + bias -> bf16  (accb aliases P, P dead now)
  k_final_node<<<((unsigned)N_NODES * 128 + 255) / 256, 256, 0, stream>>>(
      XLR, ploop, denom, bias, acc, accb);
  // 9. out = acc @ W_m2n^T  (bf16 MFMA)
  gemm_mfma<false><<<dim3(M_PAD / 128, 2), 256, 0, stream>>>(
      accb, Wm2nB, nullptr, out, N_NODES, 256, 128);
}